// Round 3
// baseline (262.990 us; speedup 1.0000x reference)
//
#include <hip/hip_runtime.h>
#include <hip/hip_bf16.h>

#define N_NODES 100000
#define N_EDGES 1600000

typedef __attribute__((ext_vector_type(8))) short short8v;   // 8 bf16 = 4 VGPRs
typedef __attribute__((ext_vector_type(4))) float float4v;   // MFMA C/D

// ---------- bf16 helpers ----------
__device__ __forceinline__ unsigned short f2bf(float f) {
    unsigned int u = __float_as_uint(f);
    u += 0x7fffu + ((u >> 16) & 1u);   // round-to-nearest-even
    return (unsigned short)(u >> 16);
}
__device__ __forceinline__ unsigned int pack2bf(float a, float b) {
    return (unsigned int)f2bf(a) | ((unsigned int)f2bf(b) << 16);
}
__device__ __forceinline__ float2 bfpair(unsigned int w) {
    return float2{__uint_as_float(w << 16), __uint_as_float(w & 0xffff0000u)};
}
// truncate-pack two fp32 -> bf16x2 in ONE v_perm (error <= 2^-8 rel, fine vs 0.0606 thr)
__device__ __forceinline__ unsigned int packtrunc(float lo, float hi) {
    return __builtin_amdgcn_perm(__float_as_uint(hi), __float_as_uint(lo), 0x07060302u);
}
__device__ __forceinline__ short8v pack8(float4 a, float4 b) {
    union { unsigned int w[4]; short8v s; } u;
    u.w[0] = packtrunc(a.x, a.y);
    u.w[1] = packtrunc(a.z, a.w);
    u.w[2] = packtrunc(b.x, b.y);
    u.w[3] = packtrunc(b.z, b.w);
    return u.s;
}

// ---------------------------------------------------------------------------
// Phase 1 (MFMA, LDS-free): AB[n][c] = x[n] @ Wbig[c]^T  (+ b1 folded into the
// A-half so phase 2 never touches b1).
//   Wbig[c][k] = W1[c & 127][(c>>7)*128 + k]
// Block: 256 thr = 4 waves; block covers 64 nodes x 256 cols; wave w covers
// cols [w*64, w*64+64). Fragments loaded DIRECTLY from global (W1 is 128 KB ->
// L2-resident; x rows shared by the block's 4 waves -> L1/L2), packed to bf16
// via v_perm truncation. Operands: A = Wbig rows (cols), B = x rows (nodes)
// => D col(lane&15) = node, D row(quad*4+r) = 4 CONSECUTIVE cols per lane ->
// one 8-B store per acc tile. No LDS, no barriers.
// ---------------------------------------------------------------------------
__global__ __launch_bounds__(256) void precompute_kernel(
    const float* __restrict__ x, const float* __restrict__ W1,
    const float* __restrict__ b1, unsigned short* __restrict__ AB) {
    const int tid = threadIdx.x;
    const int wave = tid >> 6, lane = tid & 63;
    const int quad = lane >> 4, l15 = lane & 15;
    const int n0 = blockIdx.x * 64;
    const int cbase = wave * 64;          // output col base for this wave
    const int half = wave >> 1;           // 0: A-half (W1 k 0..127), 1: B-half
    const int koff = half * 128;
    const int wrow0 = (cbase & 127) + l15;

    int nodeml[4];
#pragma unroll
    for (int i = 0; i < 4; ++i) {
        int n = n0 + i * 16 + l15;
        nodeml[i] = n < N_NODES ? n : (N_NODES - 1);   // clamp tail loads
    }

    float4v acc[4][4];   // [i: node-tile][j: col-tile]
#pragma unroll
    for (int i = 0; i < 4; ++i)
#pragma unroll
        for (int j = 0; j < 4; ++j) acc[i][j] = float4v{0.f, 0.f, 0.f, 0.f};

#pragma unroll
    for (int s = 0; s < 4; ++s) {
        const int kk = s * 32 + quad * 8;   // fp32 element offset in [0,128)
        short8v wf[4], xf[4];
#pragma unroll
        for (int j = 0; j < 4; ++j) {
            const float4* p = reinterpret_cast<const float4*>(
                W1 + (size_t)(wrow0 + j * 16) * 256 + koff + kk);
            wf[j] = pack8(p[0], p[1]);
        }
#pragma unroll
        for (int i = 0; i < 4; ++i) {
            const float4* p = reinterpret_cast<const float4*>(
                x + (size_t)nodeml[i] * 128 + kk);
            xf[i] = pack8(p[0], p[1]);
        }
#pragma unroll
        for (int i = 0; i < 4; ++i)
#pragma unroll
            for (int j = 0; j < 4; ++j)
                acc[i][j] = __builtin_amdgcn_mfma_f32_16x16x32_bf16(wf[j], xf[i], acc[i][j], 0, 0, 0);
    }

    // ---- epilogue: lane holds cols [col, col+4) of node n -> 8-B store
#pragma unroll
    for (int i = 0; i < 4; ++i) {
        const int n = n0 + i * 16 + l15;
        if (n < N_NODES) {
#pragma unroll
            for (int j = 0; j < 4; ++j) {
                const int col = cbase + j * 16 + quad * 4;
                float r0 = acc[i][j][0], r1 = acc[i][j][1];
                float r2 = acc[i][j][2], r3 = acc[i][j][3];
                if (half == 0) {   // fold b1 into the A-half exactly once
                    r0 += b1[col + 0]; r1 += b1[col + 1];
                    r2 += b1[col + 2]; r3 += b1[col + 3];
                }
                uint2 st = {pack2bf(r0, r1), pack2bf(r2, r3)};
                *reinterpret_cast<uint2*>(AB + (size_t)n * 256 + col) = st;
            }
        }
    }
}

// ---------------------------------------------------------------------------
// Phase 2: out[e] = W2 . relu(A[u] + B[v]) + b2   (b1 already folded into A)
// 16 lanes/edge, 8 edges per wave-iteration (unroll 2): all 4 idx loads and
// all 8x16-B gathers issued before any consume -> deep latency hiding.
// ---------------------------------------------------------------------------
template <bool IS64>
__device__ __forceinline__ void edge_loop(
    const long long* __restrict__ ei, const unsigned short* __restrict__ AB,
    const float* __restrict__ W2, float bias2, float* __restrict__ out,
    int wid, int nwaves, int sub, int sl) {
    const int k0 = sl * 8;
    float w2v[8];
#pragma unroll
    for (int j = 0; j < 8; ++j) w2v[j] = W2[k0 + j];
    const int* e32 = reinterpret_cast<const int*>(ei);

    for (int base = wid * 8; base < N_EDGES; base += nwaves * 8) {
        int e[2], u[2], v[2];
#pragma unroll
        for (int t = 0; t < 2; ++t) {
            e[t] = base + t * 4 + sub;    // N_EDGES % 8 == 0 -> always valid
            if (IS64) {
                u[t] = (int)ei[e[t]];
                v[t] = (int)ei[N_EDGES + e[t]];
            } else {
                u[t] = e32[e[t]];
                v[t] = e32[N_EDGES + e[t]];
            }
        }
        uint4 ua[2], vb[2];
#pragma unroll
        for (int t = 0; t < 2; ++t) {
            ua[t] = *reinterpret_cast<const uint4*>(AB + (unsigned)(u[t] * 256) + k0);
            vb[t] = *reinterpret_cast<const uint4*>(AB + (unsigned)(v[t] * 256) + 128 + k0);
        }
#pragma unroll
        for (int t = 0; t < 2; ++t) {
            unsigned int uaa[4] = {ua[t].x, ua[t].y, ua[t].z, ua[t].w};
            unsigned int vba[4] = {vb[t].x, vb[t].y, vb[t].z, vb[t].w};
            float p = 0.f;
#pragma unroll
            for (int q = 0; q < 4; ++q) {
                float2 a = bfpair(uaa[q]);
                float2 b = bfpair(vba[q]);
                float s0 = fmaxf(a.x + b.x, 0.f);
                float s1 = fmaxf(a.y + b.y, 0.f);
                p = fmaf(s0, w2v[2 * q], p);
                p = fmaf(s1, w2v[2 * q + 1], p);
            }
            p += __shfl_xor(p, 1);
            p += __shfl_xor(p, 2);
            p += __shfl_xor(p, 4);
            p += __shfl_xor(p, 8);
            if (sl == 0) out[e[t]] = p + bias2;
        }
    }
}

__global__ __launch_bounds__(256) void edge_kernel(
    const long long* __restrict__ ei, const unsigned short* __restrict__ AB,
    const float* __restrict__ W2, const float* __restrict__ b2,
    float* __restrict__ out) {
    const int lane = threadIdx.x & 63;
    const int sub = lane >> 4;
    const int sl = lane & 15;
    const float bias2 = b2[0];

    // int64-vs-int32 edge_index robustness probe (values < 1e5 -> hi words 0)
    const unsigned int hi = reinterpret_cast<const unsigned int*>(ei)[2 * lane + 1];
    const bool is64 = (__ballot(hi != 0) == 0ull);

    const int wid = (int)(((unsigned)(blockIdx.x * blockDim.x + threadIdx.x)) >> 6);
    const int nwaves = (int)(((unsigned)(gridDim.x * blockDim.x)) >> 6);

    if (is64) edge_loop<true>(ei, AB, W2, bias2, out, wid, nwaves, sub, sl);
    else      edge_loop<false>(ei, AB, W2, bias2, out, wid, nwaves, sub, sl);
}

extern "C" void kernel_launch(void* const* d_in, const int* in_sizes, int n_in,
                              void* d_out, int out_size, void* d_ws, size_t ws_size,
                              hipStream_t stream) {
    const float* x = (const float*)d_in[0];
    const long long* ei = (const long long*)d_in[1];
    const float* W1 = (const float*)d_in[2];
    const float* b1 = (const float*)d_in[3];
    const float* W2 = (const float*)d_in[4];
    const float* b2 = (const float*)d_in[5];
    float* out = (float*)d_out;
    unsigned short* AB = (unsigned short*)d_ws;   // 100000*256*2 = 51.2 MB

    precompute_kernel<<<(N_NODES + 63) / 64, 256, 0, stream>>>(x, W1, b1, AB);
    edge_kernel<<<2048, 256, 0, stream>>>(ei, AB, W2, b2, out);
}

// Round 4
// 246.763 us; speedup vs baseline: 1.0658x; 1.0658x over previous
//
#include <hip/hip_runtime.h>
#include <hip/hip_bf16.h>

#define N_NODES 100000
#define N_EDGES 1600000

typedef __attribute__((ext_vector_type(8))) short short8v;   // 8 bf16 = 4 VGPRs
typedef __attribute__((ext_vector_type(4))) float float4v;   // MFMA C/D

// ---------- bf16 helpers ----------
__device__ __forceinline__ unsigned short f2bf(float f) {
    unsigned int u = __float_as_uint(f);
    u += 0x7fffu + ((u >> 16) & 1u);   // round-to-nearest-even
    return (unsigned short)(u >> 16);
}
__device__ __forceinline__ unsigned int pack2bf(float a, float b) {
    return (unsigned int)f2bf(a) | ((unsigned int)f2bf(b) << 16);
}
__device__ __forceinline__ float2 bfpair(unsigned int w) {
    return float2{__uint_as_float(w << 16), __uint_as_float(w & 0xffff0000u)};
}

// ---------------------------------------------------------------------------
// Phase 1 (MFMA, LDS-staged — the R2 structure, which benched fastest):
//   AB[n][0:128]   = x[n] @ W1[:, :128]^T + b1   (b1 folded ONCE, A-half)
//   AB[n][128:256] = x[n] @ W1[:, 128:]^T
// Block: 256 thr (4 waves), tile 64 nodes x 128 cols; blockIdx.y = col half.
// LDS stride 136 shorts -> 2-way bank aliasing on b128 reads (free, m136).
// ---------------------------------------------------------------------------
__global__ __launch_bounds__(256) void precompute_kernel(
    const float* __restrict__ x, const float* __restrict__ W1,
    const float* __restrict__ b1, unsigned short* __restrict__ AB) {
    __shared__ unsigned short xlds[64 * 136];
    __shared__ unsigned short wlds[128 * 136];

    const int tid = threadIdx.x;
    const int n0 = blockIdx.x * 64;
    const int by = blockIdx.y;            // 0: A-half, 1: B-half
    const int jbase = by * 128;           // global AB col base

    // ---- stage W half: rows jl=0..127, W1[jl][by*128 + 0..127] -> bf16
#pragma unroll
    for (int i = 0; i < 16; ++i) {
        int fi = tid + i * 256;           // float4 idx 0..4095
        int jl = fi >> 5, c4 = fi & 31;   // row, float4-in-row
        float4 w4 = reinterpret_cast<const float4*>(W1)[(size_t)jl * 64 + by * 32 + c4];
        unsigned int* d = reinterpret_cast<unsigned int*>(&wlds[jl * 136 + c4 * 4]);
        d[0] = pack2bf(w4.x, w4.y);
        d[1] = pack2bf(w4.z, w4.w);
    }
    // ---- stage x tile: 64 rows x 128 fp32 -> bf16
#pragma unroll
    for (int i = 0; i < 8; ++i) {
        int fi = tid + i * 256;           // float4 idx 0..2047
        int n = fi >> 5, c4 = fi & 31;
        float4 v = {0.f, 0.f, 0.f, 0.f};
        if (n0 + n < N_NODES)
            v = reinterpret_cast<const float4*>(x)[(size_t)(n0 + n) * 32 + c4];
        unsigned int* d = reinterpret_cast<unsigned int*>(&xlds[n * 136 + c4 * 4]);
        d[0] = pack2bf(v.x, v.y);
        d[1] = pack2bf(v.z, v.w);
    }
    __syncthreads();

    const int wave = tid >> 6;
    const int lane = tid & 63;
    const int quad = lane >> 4;
    const int l15 = lane & 15;

    float4v acc[4][2];
#pragma unroll
    for (int i = 0; i < 4; ++i)
#pragma unroll
        for (int j = 0; j < 2; ++j) acc[i][j] = float4v{0.f, 0.f, 0.f, 0.f};

#pragma unroll
    for (int s = 0; s < 4; ++s) {
        const int k0 = s * 32 + quad * 8;
        short8v a[4], b[2];
#pragma unroll
        for (int i = 0; i < 4; ++i)
            a[i] = *reinterpret_cast<const short8v*>(&xlds[(i * 16 + l15) * 136 + k0]);
#pragma unroll
        for (int j = 0; j < 2; ++j)
            b[j] = *reinterpret_cast<const short8v*>(&wlds[(wave * 32 + j * 16 + l15) * 136 + k0]);
#pragma unroll
        for (int i = 0; i < 4; ++i)
#pragma unroll
            for (int j = 0; j < 2; ++j)
                acc[i][j] = __builtin_amdgcn_mfma_f32_16x16x32_bf16(a[i], b[j], acc[i][j], 0, 0, 0);
    }

    // ---- epilogue: C/D layout col=lane&15, row=quad*4+r; fold b1 into A-half
#pragma unroll
    for (int i = 0; i < 4; ++i) {
        const int rowb = i * 16 + quad * 4;
#pragma unroll
        for (int r = 0; r < 4; ++r) {
            const int n = n0 + rowb + r;
            if (n < N_NODES) {
#pragma unroll
                for (int j = 0; j < 2; ++j) {
                    const int lcol = wave * 32 + j * 16 + l15;
                    float val = acc[i][j][r];
                    if (by == 0) val += b1[lcol];
                    AB[(size_t)n * 256 + jbase + lcol] = f2bf(val);
                }
            }
        }
    }
}

// ---------------------------------------------------------------------------
// Phase 2: out[e] = W2 . relu(A[u] + B[v]) + b2   (b1 already in A)
// 16 lanes/edge, 4 edges/wave-iter, explicit 3-stage software pipeline:
//   stage k+2: index loads   stage k+1: AB gathers   stage k: consume/store
// Rotated SCALAR registers (not arrays) so the compiler keeps 2 gather-pairs
// + 2 idx loads in flight per thread.
// ---------------------------------------------------------------------------
template <bool IS64>
__device__ __forceinline__ void edge_loop(
    const long long* __restrict__ ei, const unsigned short* __restrict__ AB,
    const float* __restrict__ W2, float bias2, float* __restrict__ out,
    int wid, int nwaves, int sub, int sl) {
    const int k0 = sl * 8;
    float w2v[8];
#pragma unroll
    for (int j = 0; j < 8; ++j) w2v[j] = W2[k0 + j];
    const int* e32 = reinterpret_cast<const int*>(ei);

    const int stride = nwaves * 4;
    int e = wid * 4 + sub;

    // ---- preamble: idx for stages 0 and 1; gathers for stage 0
    int u0, v0, u1, v1, u2, v2;
    {
        int ec = e < N_EDGES ? e : 0;
        if (IS64) { u0 = (int)ei[ec]; v0 = (int)ei[N_EDGES + ec]; }
        else      { u0 = e32[ec];     v0 = e32[N_EDGES + ec]; }
        int e1 = e + stride; ec = e1 < N_EDGES ? e1 : 0;
        if (IS64) { u1 = (int)ei[ec]; v1 = (int)ei[N_EDGES + ec]; }
        else      { u1 = e32[ec];     v1 = e32[N_EDGES + ec]; }
    }
    uint4 a0 = *reinterpret_cast<const uint4*>(AB + (unsigned)u0 * 256 + k0);
    uint4 b0 = *reinterpret_cast<const uint4*>(AB + (unsigned)v0 * 256 + 128 + k0);

    for (; e < N_EDGES; e += stride) {
        // stage k+2: index loads (async, no consumer this iter)
        {
            int e2 = e + 2 * stride;
            int ec = e2 < N_EDGES ? e2 : 0;
            if (IS64) { u2 = (int)ei[ec]; v2 = (int)ei[N_EDGES + ec]; }
            else      { u2 = e32[ec];     v2 = e32[N_EDGES + ec]; }
        }
        // stage k+1: gathers (idx arrived ~1 iteration ago)
        uint4 a1 = *reinterpret_cast<const uint4*>(AB + (unsigned)u1 * 256 + k0);
        uint4 b1g = *reinterpret_cast<const uint4*>(AB + (unsigned)v1 * 256 + 128 + k0);
        // stage k: consume
        {
            unsigned int ua[4] = {a0.x, a0.y, a0.z, a0.w};
            unsigned int vb[4] = {b0.x, b0.y, b0.z, b0.w};
            float p = 0.f;
#pragma unroll
            for (int q = 0; q < 4; ++q) {
                float2 a = bfpair(ua[q]);
                float2 b = bfpair(vb[q]);
                float s0 = fmaxf(a.x + b.x, 0.f);
                float s1 = fmaxf(a.y + b.y, 0.f);
                p = fmaf(s0, w2v[2 * q], p);
                p = fmaf(s1, w2v[2 * q + 1], p);
            }
            p += __shfl_xor(p, 1);
            p += __shfl_xor(p, 2);
            p += __shfl_xor(p, 4);
            p += __shfl_xor(p, 8);
            if (sl == 0) out[e] = p + bias2;
        }
        // rotate
        a0 = a1; b0 = b1g; u1 = u2; v1 = v2;
    }
}

__global__ __launch_bounds__(256) void edge_kernel(
    const long long* __restrict__ ei, const unsigned short* __restrict__ AB,
    const float* __restrict__ W2, const float* __restrict__ b2,
    float* __restrict__ out) {
    const int lane = threadIdx.x & 63;
    const int sub = lane >> 4;
    const int sl = lane & 15;
    const float bias2 = b2[0];

    // int64-vs-int32 edge_index robustness probe (values < 1e5 -> hi words 0)
    const unsigned int hi = reinterpret_cast<const unsigned int*>(ei)[2 * lane + 1];
    const bool is64 = (__ballot(hi != 0) == 0ull);

    const int wid = (int)(((unsigned)(blockIdx.x * blockDim.x + threadIdx.x)) >> 6);
    const int nwaves = (int)(((unsigned)(gridDim.x * blockDim.x)) >> 6);

    if (is64) edge_loop<true>(ei, AB, W2, bias2, out, wid, nwaves, sub, sl);
    else      edge_loop<false>(ei, AB, W2, bias2, out, wid, nwaves, sub, sl);
}

extern "C" void kernel_launch(void* const* d_in, const int* in_sizes, int n_in,
                              void* d_out, int out_size, void* d_ws, size_t ws_size,
                              hipStream_t stream) {
    const float* x = (const float*)d_in[0];
    const long long* ei = (const long long*)d_in[1];
    const float* W1 = (const float*)d_in[2];
    const float* b1 = (const float*)d_in[3];
    const float* W2 = (const float*)d_in[4];
    const float* b2 = (const float*)d_in[5];
    float* out = (float*)d_out;
    unsigned short* AB = (unsigned short*)d_ws;   // 100000*256*2 = 51.2 MB

    dim3 g1((N_NODES + 63) / 64, 2);
    precompute_kernel<<<g1, 256, 0, stream>>>(x, W1, b1, AB);
    edge_kernel<<<2048, 256, 0, stream>>>(ei, AB, W2, b2, out);
}

// Round 5
// 235.503 us; speedup vs baseline: 1.1167x; 1.0478x over previous
//
#include <hip/hip_runtime.h>
#include <hip/hip_bf16.h>

#define N_NODES 100000
#define N_EDGES 1600000

typedef __attribute__((ext_vector_type(8))) short short8v;   // 8 bf16 = 4 VGPRs
typedef __attribute__((ext_vector_type(4))) float float4v;   // MFMA C/D

// ws layout: AB @0 (51,200,000 B) | xbf @51,200,000 (25,600,000 B) |
//            wbf @76,800,000 (65,536 B)  -> total 76,865,536 B
#define AB_BYTES   51200000ULL
#define XBF_OFF    51200000ULL
#define WBF_OFF    76800000ULL
#define WS_NEEDED  76865536ULL

// ---------- bf16 helpers ----------
__device__ __forceinline__ unsigned short f2bf(float f) {
    unsigned int u = __float_as_uint(f);
    u += 0x7fffu + ((u >> 16) & 1u);   // round-to-nearest-even
    return (unsigned short)(u >> 16);
}
__device__ __forceinline__ unsigned int pack2bf(float a, float b) {
    return (unsigned int)f2bf(a) | ((unsigned int)f2bf(b) << 16);
}
__device__ __forceinline__ float2 bfpair(unsigned int w) {
    return float2{__uint_as_float(w << 16), __uint_as_float(w & 0xffff0000u)};
}

// ---------------------------------------------------------------------------
// Prep: fp32 -> bf16 streaming convert (RNE, same numerics as the staged
// conversion it replaces). One float4 per thread.
// ---------------------------------------------------------------------------
__global__ __launch_bounds__(256) void conv_kernel(
    const float* __restrict__ src, unsigned short* __restrict__ dst, int n4) {
    int i = blockIdx.x * 256 + threadIdx.x;
    if (i < n4) {
        float4 v = reinterpret_cast<const float4*>(src)[i];
        uint2 o = {pack2bf(v.x, v.y), pack2bf(v.z, v.w)};
        reinterpret_cast<uint2*>(dst)[i] = o;
    }
}

// ---------------------------------------------------------------------------
// Phase 1 (MFMA): AB[n][0:128] = x@W1[:,:128]^T + b1 ; AB[n][128:256] = x@W1[:,128:]^T
// Block 256 thr (4 waves), tile 64 nodes x 128 cols; blockIdx.y = col half.
// PRECONV=true: stage pre-converted bf16 (pure 16-B copies). false: convert
// fp32 sources during staging (fallback if ws too small).
// Operand roles: A = W rows (AB-cols), B = x rows (nodes) =>
// D row(quad*4+r) = 4 consecutive AB-cols per lane -> one 8-B store per tile
// (layout verified by R3's passing bench). LDS stride 136 shorts -> 2-way
// bank aliasing on b128 reads (free, m136).
// ---------------------------------------------------------------------------
template <bool PRECONV>
__global__ __launch_bounds__(256) void precompute_kernel(
    const float* __restrict__ x, const float* __restrict__ W1,
    const unsigned short* __restrict__ xbf, const unsigned short* __restrict__ wbf,
    const float* __restrict__ b1, unsigned short* __restrict__ AB) {
    __shared__ unsigned short xlds[64 * 136];
    __shared__ unsigned short wlds[128 * 136];

    const int tid = threadIdx.x;
    const int n0 = blockIdx.x * 64;
    const int by = blockIdx.y;            // 0: A-half (+b1), 1: B-half
    const int jbase = by * 128;

    const int wave = tid >> 6;
    const int lane = tid & 63;
    const int quad = lane >> 4;
    const int l15 = lane & 15;

    // b1 broadcast into regs (before barrier); only applied when by==0
    float4 b1v[2];
#pragma unroll
    for (int j = 0; j < 2; ++j)
        b1v[j] = *reinterpret_cast<const float4*>(b1 + wave * 32 + j * 16 + quad * 4);

    if (PRECONV) {
        // ---- stage W half: 128 rows x 128 bf16, pure 16-B copies
#pragma unroll
        for (int i = 0; i < 8; ++i) {
            int fi = tid + i * 256;            // 16-B chunk idx 0..2047
            int jl = fi >> 4, c8 = fi & 15;
            uint4 v = *reinterpret_cast<const uint4*>(wbf + (size_t)jl * 256 + by * 128 + c8 * 8);
            *reinterpret_cast<uint4*>(&wlds[jl * 136 + c8 * 8]) = v;
        }
        // ---- stage x tile: 64 rows x 128 bf16
#pragma unroll
        for (int i = 0; i < 4; ++i) {
            int fi = tid + i * 256;            // chunk idx 0..1023
            int n = fi >> 4, c8 = fi & 15;
            int nn = n0 + n < N_NODES ? n0 + n : N_NODES - 1;
            uint4 v = *reinterpret_cast<const uint4*>(xbf + (size_t)nn * 128 + c8 * 8);
            *reinterpret_cast<uint4*>(&xlds[n * 136 + c8 * 8]) = v;
        }
    } else {
        // ---- fallback: convert during staging (R2 structure)
#pragma unroll
        for (int i = 0; i < 16; ++i) {
            int fi = tid + i * 256;
            int jl = fi >> 5, c4 = fi & 31;
            float4 w4 = reinterpret_cast<const float4*>(W1)[(size_t)jl * 64 + by * 32 + c4];
            unsigned int* d = reinterpret_cast<unsigned int*>(&wlds[jl * 136 + c4 * 4]);
            d[0] = pack2bf(w4.x, w4.y);
            d[1] = pack2bf(w4.z, w4.w);
        }
#pragma unroll
        for (int i = 0; i < 8; ++i) {
            int fi = tid + i * 256;
            int n = fi >> 5, c4 = fi & 31;
            float4 v = {0.f, 0.f, 0.f, 0.f};
            if (n0 + n < N_NODES)
                v = reinterpret_cast<const float4*>(x)[(size_t)(n0 + n) * 32 + c4];
            unsigned int* d = reinterpret_cast<unsigned int*>(&xlds[n * 136 + c4 * 4]);
            d[0] = pack2bf(v.x, v.y);
            d[1] = pack2bf(v.z, v.w);
        }
    }
    __syncthreads();

    float4v acc[4][2];   // [node tile][col tile]
#pragma unroll
    for (int i = 0; i < 4; ++i)
#pragma unroll
        for (int j = 0; j < 2; ++j) acc[i][j] = float4v{0.f, 0.f, 0.f, 0.f};

#pragma unroll
    for (int s = 0; s < 4; ++s) {
        const int k0 = s * 32 + quad * 8;
        short8v wf[2], xf[4];
#pragma unroll
        for (int j = 0; j < 2; ++j)
            wf[j] = *reinterpret_cast<const short8v*>(&wlds[(wave * 32 + j * 16 + l15) * 136 + k0]);
#pragma unroll
        for (int i = 0; i < 4; ++i)
            xf[i] = *reinterpret_cast<const short8v*>(&xlds[(i * 16 + l15) * 136 + k0]);
#pragma unroll
        for (int i = 0; i < 4; ++i)
#pragma unroll
            for (int j = 0; j < 2; ++j)
                acc[i][j] = __builtin_amdgcn_mfma_f32_16x16x32_bf16(wf[j], xf[i], acc[i][j], 0, 0, 0);
    }

    // ---- epilogue: lane holds AB[node][colb .. colb+3] -> 8-B store
#pragma unroll
    for (int i = 0; i < 4; ++i) {
        const int n = n0 + i * 16 + l15;
        if (n < N_NODES) {
#pragma unroll
            for (int j = 0; j < 2; ++j) {
                const int lcol = wave * 32 + j * 16 + quad * 4;
                float r0 = acc[i][j][0], r1 = acc[i][j][1];
                float r2 = acc[i][j][2], r3 = acc[i][j][3];
                if (by == 0) {
                    r0 += b1v[j].x; r1 += b1v[j].y;
                    r2 += b1v[j].z; r3 += b1v[j].w;
                }
                uint2 st = {pack2bf(r0, r1), pack2bf(r2, r3)};
                *reinterpret_cast<uint2*>(AB + (size_t)n * 256 + jbase + lcol) = st;
            }
        }
    }
}

// ---------------------------------------------------------------------------
// Phase 2: out[e] = W2 . relu(A[u] + B[v]) + b2   (b1 already folded into A)
// Best-known form (R1/R2 simple loop, 113.1 us): 16 lanes/edge, 4 edges/wave.
// ---------------------------------------------------------------------------
template <bool IS64>
__device__ __forceinline__ void edge_loop(
    const long long* __restrict__ ei, const unsigned short* __restrict__ AB,
    const float* __restrict__ W2, float bias2, float* __restrict__ out,
    int wid, int nwaves, int sub, int sl) {
    const int k0 = sl * 8;
    float w2v[8];
#pragma unroll
    for (int j = 0; j < 8; ++j) w2v[j] = W2[k0 + j];
    const int* e32 = reinterpret_cast<const int*>(ei);

    for (int base = wid * 4; base < N_EDGES; base += nwaves * 4) {
        const int e = base + sub;   // N_EDGES % 4 == 0 -> always in range
        int u, v;
        if (IS64) { u = (int)ei[e]; v = (int)ei[N_EDGES + e]; }
        else      { u = e32[e];     v = e32[N_EDGES + e]; }
        uint4 ua = *reinterpret_cast<const uint4*>(AB + (unsigned)u * 256 + k0);
        uint4 vb = *reinterpret_cast<const uint4*>(AB + (unsigned)v * 256 + 128 + k0);
        unsigned int uaa[4] = {ua.x, ua.y, ua.z, ua.w};
        unsigned int vba[4] = {vb.x, vb.y, vb.z, vb.w};
        float p = 0.f;
#pragma unroll
        for (int q = 0; q < 4; ++q) {
            float2 a = bfpair(uaa[q]);
            float2 b = bfpair(vba[q]);
            float s0 = fmaxf(a.x + b.x, 0.f);
            float s1 = fmaxf(a.y + b.y, 0.f);
            p = fmaf(s0, w2v[2 * q], p);
            p = fmaf(s1, w2v[2 * q + 1], p);
        }
        p += __shfl_xor(p, 1);
        p += __shfl_xor(p, 2);
        p += __shfl_xor(p, 4);
        p += __shfl_xor(p, 8);
        if (sl == 0) out[e] = p + bias2;
    }
}

__global__ __launch_bounds__(256) void edge_kernel(
    const long long* __restrict__ ei, const unsigned short* __restrict__ AB,
    const float* __restrict__ W2, const float* __restrict__ b2,
    float* __restrict__ out) {
    const int lane = threadIdx.x & 63;
    const int sub = lane >> 4;
    const int sl = lane & 15;
    const float bias2 = b2[0];

    // int64-vs-int32 edge_index robustness probe (values < 1e5 -> hi words 0)
    const unsigned int hi = reinterpret_cast<const unsigned int*>(ei)[2 * lane + 1];
    const bool is64 = (__ballot(hi != 0) == 0ull);

    const int wid = (int)(((unsigned)(blockIdx.x * blockDim.x + threadIdx.x)) >> 6);
    const int nwaves = (int)(((unsigned)(gridDim.x * blockDim.x)) >> 6);

    if (is64) edge_loop<true>(ei, AB, W2, bias2, out, wid, nwaves, sub, sl);
    else      edge_loop<false>(ei, AB, W2, bias2, out, wid, nwaves, sub, sl);
}

extern "C" void kernel_launch(void* const* d_in, const int* in_sizes, int n_in,
                              void* d_out, int out_size, void* d_ws, size_t ws_size,
                              hipStream_t stream) {
    const float* x = (const float*)d_in[0];
    const long long* ei = (const long long*)d_in[1];
    const float* W1 = (const float*)d_in[2];
    const float* b1 = (const float*)d_in[3];
    const float* W2 = (const float*)d_in[4];
    const float* b2 = (const float*)d_in[5];
    float* out = (float*)d_out;

    unsigned short* AB = (unsigned short*)d_ws;
    unsigned short* xbf = (unsigned short*)((char*)d_ws + XBF_OFF);
    unsigned short* wbf = (unsigned short*)((char*)d_ws + WBF_OFF);

    dim3 g1((N_NODES + 63) / 64, 2);
    if (ws_size >= WS_NEEDED) {
        const int xn4 = N_NODES * 128 / 4;   // 3,200,000
        const int wn4 = 128 * 256 / 4;       // 8,192
        conv_kernel<<<(xn4 + 255) / 256, 256, 0, stream>>>(x, xbf, xn4);
        conv_kernel<<<(wn4 + 255) / 256, 256, 0, stream>>>(W1, wbf, wn4);
        precompute_kernel<true><<<g1, 256, 0, stream>>>(x, W1, xbf, wbf, b1, AB);
    } else {
        precompute_kernel<false><<<g1, 256, 0, stream>>>(x, W1, xbf, wbf, b1, AB);
    }
    edge_kernel<<<2048, 256, 0, stream>>>(ei, AB, W2, b2, out);
}

// Round 6
// 234.932 us; speedup vs baseline: 1.1194x; 1.0024x over previous
//
#include <hip/hip_runtime.h>
#include <hip/hip_bf16.h>

#define N_NODES 100000
#define N_EDGES 1600000

typedef __attribute__((ext_vector_type(8))) short short8v;   // 8 bf16 = 4 VGPRs
typedef __attribute__((ext_vector_type(4))) float float4v;   // MFMA C/D

// ws layout: AB @0 (51,200,000 B) | xbf @51,200,000 (25,600,000 B) |
//            wbf @76,800,000 (65,536 B)  -> total 76,865,536 B
#define XBF_OFF    51200000ULL
#define WBF_OFF    76800000ULL
#define WS_NEEDED  76865536ULL

// ---------- bf16 helpers ----------
__device__ __forceinline__ unsigned short f2bf(float f) {
    unsigned int u = __float_as_uint(f);
    u += 0x7fffu + ((u >> 16) & 1u);   // round-to-nearest-even
    return (unsigned short)(u >> 16);
}
__device__ __forceinline__ unsigned int pack2bf(float a, float b) {
    return (unsigned int)f2bf(a) | ((unsigned int)f2bf(b) << 16);
}
__device__ __forceinline__ float2 bfpair(unsigned int w) {
    return float2{__uint_as_float(w << 16), __uint_as_float(w & 0xffff0000u)};
}

// ---------------------------------------------------------------------------
// Prep: fp32 -> bf16 streaming convert (RNE). One float4 per thread.
// ---------------------------------------------------------------------------
__global__ __launch_bounds__(256) void conv_kernel(
    const float* __restrict__ src, unsigned short* __restrict__ dst, int n4) {
    int i = blockIdx.x * 256 + threadIdx.x;
    if (i < n4) {
        float4 v = reinterpret_cast<const float4*>(src)[i];
        uint2 o = {pack2bf(v.x, v.y), pack2bf(v.z, v.w)};
        reinterpret_cast<uint2*>(dst)[i] = o;
    }
}

// ---------------------------------------------------------------------------
// Phase 1 (MFMA): AB[n][0:128] = x@W1[:,:128]^T + b1 ; AB[n][128:256] = x@W1[:,128:]^T
// Unchanged from R5 (best measured). Block 256 thr, tile 64 nodes x 128 cols;
// blockIdx.y = col half. A = W rows, B = x rows => lane holds 4 consecutive
// AB-cols -> 8-B stores. LDS stride 136 (2-way aliasing free, m136).
// ---------------------------------------------------------------------------
template <bool PRECONV>
__global__ __launch_bounds__(256) void precompute_kernel(
    const float* __restrict__ x, const float* __restrict__ W1,
    const unsigned short* __restrict__ xbf, const unsigned short* __restrict__ wbf,
    const float* __restrict__ b1, unsigned short* __restrict__ AB) {
    __shared__ unsigned short xlds[64 * 136];
    __shared__ unsigned short wlds[128 * 136];

    const int tid = threadIdx.x;
    const int n0 = blockIdx.x * 64;
    const int by = blockIdx.y;            // 0: A-half (+b1), 1: B-half
    const int jbase = by * 128;

    const int wave = tid >> 6;
    const int lane = tid & 63;
    const int quad = lane >> 4;
    const int l15 = lane & 15;

    float4 b1v[2];
#pragma unroll
    for (int j = 0; j < 2; ++j)
        b1v[j] = *reinterpret_cast<const float4*>(b1 + wave * 32 + j * 16 + quad * 4);

    if (PRECONV) {
#pragma unroll
        for (int i = 0; i < 8; ++i) {
            int fi = tid + i * 256;            // 16-B chunk idx 0..2047
            int jl = fi >> 4, c8 = fi & 15;
            uint4 v = *reinterpret_cast<const uint4*>(wbf + (size_t)jl * 256 + by * 128 + c8 * 8);
            *reinterpret_cast<uint4*>(&wlds[jl * 136 + c8 * 8]) = v;
        }
#pragma unroll
        for (int i = 0; i < 4; ++i) {
            int fi = tid + i * 256;            // chunk idx 0..1023
            int n = fi >> 4, c8 = fi & 15;
            int nn = n0 + n < N_NODES ? n0 + n : N_NODES - 1;
            uint4 v = *reinterpret_cast<const uint4*>(xbf + (size_t)nn * 128 + c8 * 8);
            *reinterpret_cast<uint4*>(&xlds[n * 136 + c8 * 8]) = v;
        }
    } else {
#pragma unroll
        for (int i = 0; i < 16; ++i) {
            int fi = tid + i * 256;
            int jl = fi >> 5, c4 = fi & 31;
            float4 w4 = reinterpret_cast<const float4*>(W1)[(size_t)jl * 64 + by * 32 + c4];
            unsigned int* d = reinterpret_cast<unsigned int*>(&wlds[jl * 136 + c4 * 4]);
            d[0] = pack2bf(w4.x, w4.y);
            d[1] = pack2bf(w4.z, w4.w);
        }
#pragma unroll
        for (int i = 0; i < 8; ++i) {
            int fi = tid + i * 256;
            int n = fi >> 5, c4 = fi & 31;
            float4 v = {0.f, 0.f, 0.f, 0.f};
            if (n0 + n < N_NODES)
                v = reinterpret_cast<const float4*>(x)[(size_t)(n0 + n) * 32 + c4];
            unsigned int* d = reinterpret_cast<unsigned int*>(&xlds[n * 136 + c4 * 4]);
            d[0] = pack2bf(v.x, v.y);
            d[1] = pack2bf(v.z, v.w);
        }
    }
    __syncthreads();

    float4v acc[4][2];   // [node tile][col tile]
#pragma unroll
    for (int i = 0; i < 4; ++i)
#pragma unroll
        for (int j = 0; j < 2; ++j) acc[i][j] = float4v{0.f, 0.f, 0.f, 0.f};

#pragma unroll
    for (int s = 0; s < 4; ++s) {
        const int k0 = s * 32 + quad * 8;
        short8v wf[2], xf[4];
#pragma unroll
        for (int j = 0; j < 2; ++j)
            wf[j] = *reinterpret_cast<const short8v*>(&wlds[(wave * 32 + j * 16 + l15) * 136 + k0]);
#pragma unroll
        for (int i = 0; i < 4; ++i)
            xf[i] = *reinterpret_cast<const short8v*>(&xlds[(i * 16 + l15) * 136 + k0]);
#pragma unroll
        for (int i = 0; i < 4; ++i)
#pragma unroll
            for (int j = 0; j < 2; ++j)
                acc[i][j] = __builtin_amdgcn_mfma_f32_16x16x32_bf16(wf[j], xf[i], acc[i][j], 0, 0, 0);
    }

#pragma unroll
    for (int i = 0; i < 4; ++i) {
        const int n = n0 + i * 16 + l15;
        if (n < N_NODES) {
#pragma unroll
            for (int j = 0; j < 2; ++j) {
                const int lcol = wave * 32 + j * 16 + quad * 4;
                float r0 = acc[i][j][0], r1 = acc[i][j][1];
                float r2 = acc[i][j][2], r3 = acc[i][j][3];
                if (by == 0) {
                    r0 += b1v[j].x; r1 += b1v[j].y;
                    r2 += b1v[j].z; r3 += b1v[j].w;
                }
                uint2 st = {pack2bf(r0, r1), pack2bf(r2, r3)};
                *reinterpret_cast<uint2*>(AB + (size_t)n * 256 + jbase + lcol) = st;
            }
        }
    }
}

// ---------------------------------------------------------------------------
// Phase 2: out[e] = W2 . relu(A[u] + B[v]) + b2   (b1 already folded into A)
// NEW: 4 lanes/edge, 16 edges/wave-iter. Each lane covers 32 features and
// issues EIGHT independent 16-B gathers (4 from A[u], 4 from B[v]) before any
// consume -> 4x the per-lane in-flight bytes vs the 2-load version; the
// compiler cannot serialize intra-iteration independent loads (s_waitcnt
// vmcnt(N>0) consume pattern keeps them outstanding).
// __launch_bounds__(256,4): allow up to 128 VGPR, 4 waves/SIMD.
// ---------------------------------------------------------------------------
template <bool IS64>
__device__ __forceinline__ void edge_loop(
    const long long* __restrict__ ei, const unsigned short* __restrict__ AB,
    const float* __restrict__ W2, float bias2, float* __restrict__ out,
    int wid, int nwaves, int eg, int sl) {
    const int k0 = sl * 32;              // feature base for this lane
    float4 w2q[8];
#pragma unroll
    for (int j = 0; j < 8; ++j)
        w2q[j] = *reinterpret_cast<const float4*>(W2 + k0 + j * 4);
    const int* e32 = reinterpret_cast<const int*>(ei);

    for (int base = wid * 16; base < N_EDGES; base += nwaves * 16) {
        const int e = base + eg;          // N_EDGES % 16 == 0 -> in range
        int u, v;
        if (IS64) { u = (int)ei[e]; v = (int)ei[N_EDGES + e]; }
        else      { u = e32[e];     v = e32[N_EDGES + e]; }

        const unsigned short* pa = AB + (unsigned)u * 256 + k0;
        const unsigned short* pb = AB + (unsigned)v * 256 + 128 + k0;
        uint4 a[4], b[4];
#pragma unroll
        for (int t = 0; t < 4; ++t) a[t] = *reinterpret_cast<const uint4*>(pa + t * 8);
#pragma unroll
        for (int t = 0; t < 4; ++t) b[t] = *reinterpret_cast<const uint4*>(pb + t * 8);

        float p = 0.f;
#pragma unroll
        for (int t = 0; t < 4; ++t) {
            unsigned int aw[4] = {a[t].x, a[t].y, a[t].z, a[t].w};
            unsigned int bw[4] = {b[t].x, b[t].y, b[t].z, b[t].w};
#pragma unroll
            for (int q = 0; q < 4; ++q) {
                float2 av = bfpair(aw[q]);
                float2 bv = bfpair(bw[q]);
                float s0 = fmaxf(av.x + bv.x, 0.f);
                float s1 = fmaxf(av.y + bv.y, 0.f);
                const float* wq = reinterpret_cast<const float*>(&w2q[t * 2 + (q >> 1)]);
                p = fmaf(s0, wq[(q & 1) * 2 + 0], p);
                p = fmaf(s1, wq[(q & 1) * 2 + 1], p);
            }
        }
        p += __shfl_xor(p, 1);
        p += __shfl_xor(p, 2);
        if (sl == 0) out[e] = p + bias2;
    }
}

__global__ __launch_bounds__(256, 4) void edge_kernel(
    const long long* __restrict__ ei, const unsigned short* __restrict__ AB,
    const float* __restrict__ W2, const float* __restrict__ b2,
    float* __restrict__ out) {
    const int lane = threadIdx.x & 63;
    const int eg = lane >> 2;     // edge group 0..15 within wave
    const int sl = lane & 3;      // sub-lane within edge
    const float bias2 = b2[0];

    // int64-vs-int32 edge_index robustness probe (values < 1e5 -> hi words 0)
    const unsigned int hi = reinterpret_cast<const unsigned int*>(ei)[2 * lane + 1];
    const bool is64 = (__ballot(hi != 0) == 0ull);

    const int wid = (int)(((unsigned)(blockIdx.x * blockDim.x + threadIdx.x)) >> 6);
    const int nwaves = (int)(((unsigned)(gridDim.x * blockDim.x)) >> 6);

    if (is64) edge_loop<true>(ei, AB, W2, bias2, out, wid, nwaves, eg, sl);
    else      edge_loop<false>(ei, AB, W2, bias2, out, wid, nwaves, eg, sl);
}

extern "C" void kernel_launch(void* const* d_in, const int* in_sizes, int n_in,
                              void* d_out, int out_size, void* d_ws, size_t ws_size,
                              hipStream_t stream) {
    const float* x = (const float*)d_in[0];
    const long long* ei = (const long long*)d_in[1];
    const float* W1 = (const float*)d_in[2];
    const float* b1 = (const float*)d_in[3];
    const float* W2 = (const float*)d_in[4];
    const float* b2 = (const float*)d_in[5];
    float* out = (float*)d_out;

    unsigned short* AB = (unsigned short*)d_ws;
    unsigned short* xbf = (unsigned short*)((char*)d_ws + XBF_OFF);
    unsigned short* wbf = (unsigned short*)((char*)d_ws + WBF_OFF);

    dim3 g1((N_NODES + 63) / 64, 2);
    if (ws_size >= WS_NEEDED) {
        const int xn4 = N_NODES * 128 / 4;   // 3,200,000
        const int wn4 = 128 * 256 / 4;       // 8,192
        conv_kernel<<<(xn4 + 255) / 256, 256, 0, stream>>>(x, xbf, xn4);
        conv_kernel<<<(wn4 + 255) / 256, 256, 0, stream>>>(W1, wbf, wn4);
        precompute_kernel<true><<<g1, 256, 0, stream>>>(x, W1, xbf, wbf, b1, AB);
    } else {
        precompute_kernel<false><<<g1, 256, 0, stream>>>(x, W1, xbf, wbf, b1, AB);
    }
    edge_kernel<<<2048, 256, 0, stream>>>(ei, AB, W2, b2, out);
}

// Round 7
// 223.089 us; speedup vs baseline: 1.1789x; 1.0531x over previous
//
#include <hip/hip_runtime.h>
#include <hip/hip_bf16.h>

#define N_NODES 100000
#define N_EDGES 1600000
#define NT_TILES 1563          // ceil(N_NODES/64)
#define PRE_BLKX 392           // 392*4 = 1568 >= 1563 node tiles

typedef __attribute__((ext_vector_type(8))) short short8v;   // 8 bf16 = 4 VGPRs
typedef __attribute__((ext_vector_type(4))) float float4v;   // MFMA C/D

// ---------- bf16 helpers ----------
__device__ __forceinline__ unsigned short f2bf(float f) {
    unsigned int u = __float_as_uint(f);
    u += 0x7fffu + ((u >> 16) & 1u);   // round-to-nearest-even
    return (unsigned short)(u >> 16);
}
__device__ __forceinline__ unsigned int pack2bf(float a, float b) {
    return (unsigned int)f2bf(a) | ((unsigned int)f2bf(b) << 16);
}
__device__ __forceinline__ float2 bfpair(unsigned int w) {
    return float2{__uint_as_float(w << 16), __uint_as_float(w & 0xffff0000u)};
}

// ---------------------------------------------------------------------------
// Phase 1 (MFMA, persistent node-loop):
//   AB[n][0:128] = x@W1[:,:128]^T + b1 ; AB[n][128:256] = x@W1[:,128:]^T
// Grid (392, 2): blockIdx.y = col half; each block stages its W-half ONCE
// (128x128 fp32 -> bf16, 34.8 KB LDS) then loops over ~4 node tiles of 64.
// Pipeline per tile: regs->LDS(convert) | barrier | issue next tile's global
// fp32 loads into regs, MFMA from LDS, epilogue store | barrier.
// Global x-load latency hides behind the 64-MFMA compute block.
// LDS 52 KB -> 3 blocks/CU (12 waves). Stride 136 shorts: 2-way bank
// aliasing on b128 reads = free (m136).
// Operands: A = W rows (AB-cols), B = x rows (nodes) => lane holds 4
// consecutive AB-cols -> 8-B stores (layout verified R3-R6 passing benches).
// ---------------------------------------------------------------------------
__global__ __launch_bounds__(256) void precompute_kernel(
    const float* __restrict__ x, const float* __restrict__ W1,
    const float* __restrict__ b1, unsigned short* __restrict__ AB) {
    __shared__ unsigned short wlds[128 * 136];
    __shared__ unsigned short xlds[64 * 136];

    const int tid = threadIdx.x;
    const int by = blockIdx.y;            // 0: A-half (+b1), 1: B-half
    const int jbase = by * 128;

    const int wave = tid >> 6;
    const int lane = tid & 63;
    const int quad = lane >> 4;
    const int l15 = lane & 15;

    // b1 into regs (only applied when by==0)
    float4 b1v[2];
#pragma unroll
    for (int j = 0; j < 2; ++j)
        b1v[j] = *reinterpret_cast<const float4*>(b1 + wave * 32 + j * 16 + quad * 4);

    // ---- stage W half ONCE: rows jl=0..127, W1[jl][by*128 + 0..127] -> bf16
#pragma unroll
    for (int i = 0; i < 16; ++i) {
        int fi = tid + i * 256;           // float4 idx 0..4095
        int jl = fi >> 5, c4 = fi & 31;
        float4 w4 = reinterpret_cast<const float4*>(W1)[(size_t)jl * 64 + by * 32 + c4];
        unsigned int* d = reinterpret_cast<unsigned int*>(&wlds[jl * 136 + c4 * 4]);
        d[0] = pack2bf(w4.x, w4.y);
        d[1] = pack2bf(w4.z, w4.w);
    }

    // ---- prologue: load first tile's x (fp32) into regs
    float4 xr[8];
    int t = blockIdx.x;
#pragma unroll
    for (int i = 0; i < 8; ++i) {
        int fi = tid + i * 256;           // float4 idx 0..2047
        int n = fi >> 5, c4 = fi & 31;
        int nn = t * 64 + n; nn = nn < N_NODES ? nn : N_NODES - 1;
        xr[i] = reinterpret_cast<const float4*>(x)[(size_t)nn * 32 + c4];
    }

    for (; t < NT_TILES; t += PRE_BLKX) {
        __syncthreads();   // prev tile's LDS reads done (also covers W-ready)
        // ---- regs -> LDS (convert fp32 -> bf16, RNE)
#pragma unroll
        for (int i = 0; i < 8; ++i) {
            int fi = tid + i * 256;
            int n = fi >> 5, c4 = fi & 31;
            unsigned int* d = reinterpret_cast<unsigned int*>(&xlds[n * 136 + c4 * 4]);
            d[0] = pack2bf(xr[i].x, xr[i].y);
            d[1] = pack2bf(xr[i].z, xr[i].w);
        }
        __syncthreads();

        // ---- issue next tile's global loads (consumed after next barrier)
        const int tn = t + PRE_BLKX;
        if (tn < NT_TILES) {
#pragma unroll
            for (int i = 0; i < 8; ++i) {
                int fi = tid + i * 256;
                int n = fi >> 5, c4 = fi & 31;
                int nn = tn * 64 + n; nn = nn < N_NODES ? nn : N_NODES - 1;
                xr[i] = reinterpret_cast<const float4*>(x)[(size_t)nn * 32 + c4];
            }
        }

        // ---- MFMA over this tile
        float4v acc[4][2];   // [node tile][col tile]
#pragma unroll
        for (int i = 0; i < 4; ++i)
#pragma unroll
            for (int j = 0; j < 2; ++j) acc[i][j] = float4v{0.f, 0.f, 0.f, 0.f};

#pragma unroll
        for (int s = 0; s < 4; ++s) {
            const int k0 = s * 32 + quad * 8;
            short8v wf[2], xf[4];
#pragma unroll
            for (int j = 0; j < 2; ++j)
                wf[j] = *reinterpret_cast<const short8v*>(&wlds[(wave * 32 + j * 16 + l15) * 136 + k0]);
#pragma unroll
            for (int i = 0; i < 4; ++i)
                xf[i] = *reinterpret_cast<const short8v*>(&xlds[(i * 16 + l15) * 136 + k0]);
#pragma unroll
            for (int i = 0; i < 4; ++i)
#pragma unroll
                for (int j = 0; j < 2; ++j)
                    acc[i][j] = __builtin_amdgcn_mfma_f32_16x16x32_bf16(wf[j], xf[i], acc[i][j], 0, 0, 0);
        }

        // ---- epilogue: lane holds AB[node][colb..colb+3] -> 8-B store
        const int n0 = t * 64;
#pragma unroll
        for (int i = 0; i < 4; ++i) {
            const int n = n0 + i * 16 + l15;
            if (n < N_NODES) {
#pragma unroll
                for (int j = 0; j < 2; ++j) {
                    const int lcol = wave * 32 + j * 16 + quad * 4;
                    float r0 = acc[i][j][0], r1 = acc[i][j][1];
                    float r2 = acc[i][j][2], r3 = acc[i][j][3];
                    if (by == 0) {
                        r0 += b1v[j].x; r1 += b1v[j].y;
                        r2 += b1v[j].z; r3 += b1v[j].w;
                    }
                    uint2 st = {pack2bf(r0, r1), pack2bf(r2, r3)};
                    *reinterpret_cast<uint2*>(AB + (size_t)n * 256 + jbase + lcol) = st;
                }
            }
        }
    }
}

// ---------------------------------------------------------------------------
// Phase 2: out[e] = W2 . relu(A[u] + B[v]) + b2   (b1 already folded into A)
// Best-known (R6, 111.6 us): 4 lanes/edge, 16 edges/wave-iter, 8 independent
// 16-B gathers in flight per lane. Pinned at the ~3.5 TB/s random-gather
// service ceiling (R6 experiment: 2x in-flight, identical time).
// ---------------------------------------------------------------------------
template <bool IS64>
__device__ __forceinline__ void edge_loop(
    const long long* __restrict__ ei, const unsigned short* __restrict__ AB,
    const float* __restrict__ W2, float bias2, float* __restrict__ out,
    int wid, int nwaves, int eg, int sl) {
    const int k0 = sl * 32;              // feature base for this lane
    float4 w2q[8];
#pragma unroll
    for (int j = 0; j < 8; ++j)
        w2q[j] = *reinterpret_cast<const float4*>(W2 + k0 + j * 4);
    const int* e32 = reinterpret_cast<const int*>(ei);

    for (int base = wid * 16; base < N_EDGES; base += nwaves * 16) {
        const int e = base + eg;          // N_EDGES % 16 == 0 -> in range
        int u, v;
        if (IS64) { u = (int)ei[e]; v = (int)ei[N_EDGES + e]; }
        else      { u = e32[e];     v = e32[N_EDGES + e]; }

        const unsigned short* pa = AB + (unsigned)u * 256 + k0;
        const unsigned short* pb = AB + (unsigned)v * 256 + 128 + k0;
        uint4 a[4], b[4];
#pragma unroll
        for (int t = 0; t < 4; ++t) a[t] = *reinterpret_cast<const uint4*>(pa + t * 8);
#pragma unroll
        for (int t = 0; t < 4; ++t) b[t] = *reinterpret_cast<const uint4*>(pb + t * 8);

        float p = 0.f;
#pragma unroll
        for (int t = 0; t < 4; ++t) {
            unsigned int aw[4] = {a[t].x, a[t].y, a[t].z, a[t].w};
            unsigned int bw[4] = {b[t].x, b[t].y, b[t].z, b[t].w};
#pragma unroll
            for (int q = 0; q < 4; ++q) {
                float2 av = bfpair(aw[q]);
                float2 bv = bfpair(bw[q]);
                float s0 = fmaxf(av.x + bv.x, 0.f);
                float s1 = fmaxf(av.y + bv.y, 0.f);
                const float* wq = reinterpret_cast<const float*>(&w2q[t * 2 + (q >> 1)]);
                p = fmaf(s0, wq[(q & 1) * 2 + 0], p);
                p = fmaf(s1, wq[(q & 1) * 2 + 1], p);
            }
        }
        p += __shfl_xor(p, 1);
        p += __shfl_xor(p, 2);
        if (sl == 0) out[e] = p + bias2;
    }
}

__global__ __launch_bounds__(256, 4) void edge_kernel(
    const long long* __restrict__ ei, const unsigned short* __restrict__ AB,
    const float* __restrict__ W2, const float* __restrict__ b2,
    float* __restrict__ out) {
    const int lane = threadIdx.x & 63;
    const int eg = lane >> 2;     // edge group 0..15 within wave
    const int sl = lane & 3;      // sub-lane within edge
    const float bias2 = b2[0];

    // int64-vs-int32 edge_index robustness probe (values < 1e5 -> hi words 0)
    const unsigned int hi = reinterpret_cast<const unsigned int*>(ei)[2 * lane + 1];
    const bool is64 = (__ballot(hi != 0) == 0ull);

    const int wid = (int)(((unsigned)(blockIdx.x * blockDim.x + threadIdx.x)) >> 6);
    const int nwaves = (int)(((unsigned)(gridDim.x * blockDim.x)) >> 6);

    if (is64) edge_loop<true>(ei, AB, W2, bias2, out, wid, nwaves, eg, sl);
    else      edge_loop<false>(ei, AB, W2, bias2, out, wid, nwaves, eg, sl);
}

extern "C" void kernel_launch(void* const* d_in, const int* in_sizes, int n_in,
                              void* d_out, int out_size, void* d_ws, size_t ws_size,
                              hipStream_t stream) {
    const float* x = (const float*)d_in[0];
    const long long* ei = (const long long*)d_in[1];
    const float* W1 = (const float*)d_in[2];
    const float* b1 = (const float*)d_in[3];
    const float* W2 = (const float*)d_in[4];
    const float* b2 = (const float*)d_in[5];
    float* out = (float*)d_out;

    unsigned short* AB = (unsigned short*)d_ws;   // 100000*256*2 = 51.2 MB

    dim3 g1(PRE_BLKX, 2);
    precompute_kernel<<<g1, 256, 0, stream>>>(x, W1, b1, AB);
    edge_kernel<<<2048, 256, 0, stream>>>(ei, AB, W2, b2, out);
}

// Round 8
// 177.136 us; speedup vs baseline: 1.4847x; 1.2594x over previous
//
#include <hip/hip_runtime.h>
#include <hip/hip_bf16.h>

#define N_NODES 100000
#define N_EDGES 1600000
#define NT_TILES 1563          // ceil(N_NODES/64)
#define PRE_BLKX 392           // 392*4 = 1568 >= 1563 node tiles

// ws layout: Aq @0 (12.8 MB) | Bq @12.8M (12.8 MB) | sA @25.6M (400 KB) |
//            sB @26.0M (400 KB)  -> 26.4 MB total (ws provided >= 76 MB)
#define BQ_OFF 12800000
#define SA_OFF 25600000
#define SB_OFF 26000000

typedef __attribute__((ext_vector_type(8))) short short8v;   // 8 bf16 = 4 VGPRs
typedef __attribute__((ext_vector_type(4))) float float4v;   // MFMA C/D

// ---------- bf16 helpers ----------
__device__ __forceinline__ unsigned short f2bf(float f) {
    unsigned int u = __float_as_uint(f);
    u += 0x7fffu + ((u >> 16) & 1u);   // round-to-nearest-even
    return (unsigned short)(u >> 16);
}
__device__ __forceinline__ unsigned int pack2bf(float a, float b) {
    return (unsigned int)f2bf(a) | ((unsigned int)f2bf(b) << 16);
}
__device__ __forceinline__ float2 bfpair(unsigned int w) {
    return float2{__uint_as_float(w << 16), __uint_as_float(w & 0xffff0000u)};
}
__device__ __forceinline__ float sbyte2f(unsigned int w, int i) {
    return (float)((signed char)(w >> (8 * i)));
}

// ---------------------------------------------------------------------------
// Phase 1 (MFMA, persistent node-loop) + int8 row quantization:
//   by==0: Aq[n][c] = q(x[n]@W1[c,:128] + b1[c]),  sA[n] = rowmax/127
//   by==1: Bq[n][c] = q(x[n]@W1[c,128:]),          sB[n] = rowmax/127
// Structure = R7 winner (W staged once/block, 4-tile node loop, x prefetch in
// regs) + new epilogue: acc -> LDS (bf16, stride 132) -> per-row max via quad
// shfl -> int8 quantize -> 32-B stores. LDS stride 136/132: 2-way bank
// aliasing on the hot reads = free (m136).
// ---------------------------------------------------------------------------
__global__ __launch_bounds__(256) void precompute_kernel(
    const float* __restrict__ x, const float* __restrict__ W1,
    const float* __restrict__ b1, signed char* __restrict__ Aq,
    signed char* __restrict__ Bq, float* __restrict__ sA,
    float* __restrict__ sB) {
    __shared__ unsigned short wlds[128 * 136];
    __shared__ unsigned short xlds[64 * 136];   // input tile AND acc staging

    const int tid = threadIdx.x;
    const int by = blockIdx.y;            // 0: A-half (+b1), 1: B-half
    signed char* __restrict__ Q = by ? Bq : Aq;
    float* __restrict__ S = by ? sB : sA;

    const int wave = tid >> 6;
    const int lane = tid & 63;
    const int quad = lane >> 4;
    const int l15 = lane & 15;

    float4 b1v[2];
#pragma unroll
    for (int j = 0; j < 2; ++j)
        b1v[j] = *reinterpret_cast<const float4*>(b1 + wave * 32 + j * 16 + quad * 4);

    // ---- stage W half ONCE: W1[jl][by*128 + 0..127] -> bf16
#pragma unroll
    for (int i = 0; i < 16; ++i) {
        int fi = tid + i * 256;
        int jl = fi >> 5, c4 = fi & 31;
        float4 w4 = reinterpret_cast<const float4*>(W1)[(size_t)jl * 64 + by * 32 + c4];
        unsigned int* d = reinterpret_cast<unsigned int*>(&wlds[jl * 136 + c4 * 4]);
        d[0] = pack2bf(w4.x, w4.y);
        d[1] = pack2bf(w4.z, w4.w);
    }

    // ---- prologue: first tile's x into regs
    float4 xr[8];
    int t = blockIdx.x;
#pragma unroll
    for (int i = 0; i < 8; ++i) {
        int fi = tid + i * 256;
        int n = fi >> 5, c4 = fi & 31;
        int nn = t * 64 + n; nn = nn < N_NODES ? nn : N_NODES - 1;
        xr[i] = reinterpret_cast<const float4*>(x)[(size_t)nn * 32 + c4];
    }

    for (; t < NT_TILES; t += PRE_BLKX) {
        __syncthreads();   // prev epilogue's LDS reads done (covers W too)
#pragma unroll
        for (int i = 0; i < 8; ++i) {
            int fi = tid + i * 256;
            int n = fi >> 5, c4 = fi & 31;
            unsigned int* d = reinterpret_cast<unsigned int*>(&xlds[n * 136 + c4 * 4]);
            d[0] = pack2bf(xr[i].x, xr[i].y);
            d[1] = pack2bf(xr[i].z, xr[i].w);
        }
        __syncthreads();

        const int tn = t + PRE_BLKX;
        if (tn < NT_TILES) {
#pragma unroll
            for (int i = 0; i < 8; ++i) {
                int fi = tid + i * 256;
                int n = fi >> 5, c4 = fi & 31;
                int nn = tn * 64 + n; nn = nn < N_NODES ? nn : N_NODES - 1;
                xr[i] = reinterpret_cast<const float4*>(x)[(size_t)nn * 32 + c4];
            }
        }

        float4v acc[4][2];
#pragma unroll
        for (int i = 0; i < 4; ++i)
#pragma unroll
            for (int j = 0; j < 2; ++j) acc[i][j] = float4v{0.f, 0.f, 0.f, 0.f};

#pragma unroll
        for (int s = 0; s < 4; ++s) {
            const int k0 = s * 32 + quad * 8;
            short8v wf[2], xf[4];
#pragma unroll
            for (int j = 0; j < 2; ++j)
                wf[j] = *reinterpret_cast<const short8v*>(&wlds[(wave * 32 + j * 16 + l15) * 136 + k0]);
#pragma unroll
            for (int i = 0; i < 4; ++i)
                xf[i] = *reinterpret_cast<const short8v*>(&xlds[(i * 16 + l15) * 136 + k0]);
#pragma unroll
            for (int i = 0; i < 4; ++i)
#pragma unroll
                for (int j = 0; j < 2; ++j)
                    acc[i][j] = __builtin_amdgcn_mfma_f32_16x16x32_bf16(wf[j], xf[i], acc[i][j], 0, 0, 0);
        }
        __syncthreads();   // all xlds input reads done -> reuse as staging

        // ---- acc (+b1) -> LDS staging, bf16, stride 132 shorts
#pragma unroll
        for (int i = 0; i < 4; ++i) {
            const int nl = i * 16 + l15;
#pragma unroll
            for (int j = 0; j < 2; ++j) {
                const int colb = wave * 32 + j * 16 + quad * 4;
                float r0 = acc[i][j][0], r1 = acc[i][j][1];
                float r2 = acc[i][j][2], r3 = acc[i][j][3];
                if (by == 0) {
                    r0 += b1v[j].x; r1 += b1v[j].y;
                    r2 += b1v[j].z; r3 += b1v[j].w;
                }
                uint2 st = {pack2bf(r0, r1), pack2bf(r2, r3)};
                *reinterpret_cast<uint2*>(&xlds[nl * 132 + colb]) = st;
            }
        }
        __syncthreads();

        // ---- per-row max + int8 quantize; thread = (row = tid>>2, part = tid&3)
        const int row = tid >> 2, part = tid & 3;
        const int n = t * 64 + row;
        uint4 wv[4];
#pragma unroll
        for (int q = 0; q < 4; ++q)
            wv[q] = *reinterpret_cast<const uint4*>(&xlds[row * 132 + part * 32 + q * 8]);

        float m = 1e-6f;
#pragma unroll
        for (int q = 0; q < 4; ++q) {
            unsigned int ws[4] = {wv[q].x, wv[q].y, wv[q].z, wv[q].w};
#pragma unroll
            for (int w = 0; w < 4; ++w) {
                float2 f = bfpair(ws[w]);
                m = fmaxf(m, fmaxf(fabsf(f.x), fabsf(f.y)));
            }
        }
        m = fmaxf(m, __shfl_xor(m, 1));   // quad (4 parts of one row) reduce
        m = fmaxf(m, __shfl_xor(m, 2));
        const float inv = 127.0f / m;

        unsigned int ob[8];
#pragma unroll
        for (int q = 0; q < 4; ++q) {
            unsigned int ws[4] = {wv[q].x, wv[q].y, wv[q].z, wv[q].w};
#pragma unroll
            for (int w = 0; w < 2; ++w) {
                float2 f0 = bfpair(ws[2 * w + 0]);
                float2 f1 = bfpair(ws[2 * w + 1]);
                int q0 = (int)rintf(f0.x * inv), q1 = (int)rintf(f0.y * inv);
                int q2 = (int)rintf(f1.x * inv), q3 = (int)rintf(f1.y * inv);
                ob[q * 2 + w] = (q0 & 0xff) | ((q1 & 0xff) << 8) |
                                ((q2 & 0xff) << 16) | ((unsigned)q3 << 24);
            }
        }
        if (n < N_NODES) {
            uint4 s0 = {ob[0], ob[1], ob[2], ob[3]};
            uint4 s1 = {ob[4], ob[5], ob[6], ob[7]};
            uint4* dst = reinterpret_cast<uint4*>(Q + (size_t)n * 128 + part * 32);
            dst[0] = s0;
            dst[1] = s1;
            if (part == 0) S[n] = m * (1.0f / 127.0f);
        }
    }
}

// ---------------------------------------------------------------------------
// Phase 2: out[e] = W2 . relu(sA[u]*Aq[u] + sB[v]*Bq[v]) + b2
// 4 lanes/edge (32 int8 features = 32 B per half per lane -> 2x16-B gathers
// per half), 16 edges/wave-iter. int8 halves gather bytes AND makes each
// row-half one 128-B cache line.
// ---------------------------------------------------------------------------
template <bool IS64>
__device__ __forceinline__ void edge_loop(
    const long long* __restrict__ ei, const signed char* __restrict__ Aq,
    const signed char* __restrict__ Bq, const float* __restrict__ sA,
    const float* __restrict__ sB, const float* __restrict__ W2, float bias2,
    float* __restrict__ out, int wid, int nwaves, int eg, int sl) {
    const int k0 = sl * 32;              // feature base for this lane
    float4 w2q[8];
#pragma unroll
    for (int j = 0; j < 8; ++j)
        w2q[j] = *reinterpret_cast<const float4*>(W2 + k0 + j * 4);
    const int* e32 = reinterpret_cast<const int*>(ei);

    for (int base = wid * 16; base < N_EDGES; base += nwaves * 16) {
        const int e = base + eg;          // N_EDGES % 16 == 0 -> in range
        int u, v;
        if (IS64) { u = (int)ei[e]; v = (int)ei[N_EDGES + e]; }
        else      { u = e32[e];     v = e32[N_EDGES + e]; }

        const uint4* pa = reinterpret_cast<const uint4*>(Aq + (unsigned)u * 128 + k0);
        const uint4* pb = reinterpret_cast<const uint4*>(Bq + (unsigned)v * 128 + k0);
        uint4 a0 = pa[0], a1 = pa[1];
        uint4 b0 = pb[0], b1w = pb[1];
        const float su = sA[u];
        const float sv = sB[v];

        unsigned int aw[8] = {a0.x, a0.y, a0.z, a0.w, a1.x, a1.y, a1.z, a1.w};
        unsigned int bw[8] = {b0.x, b0.y, b0.z, b0.w, b1w.x, b1w.y, b1w.z, b1w.w};

        float p = 0.f;
#pragma unroll
        for (int wi = 0; wi < 8; ++wi) {
            const float* w2p = reinterpret_cast<const float*>(&w2q[wi >> 1]) + (wi & 1) * 0;
            // features wi*4 .. wi*4+3 ; w2 element = w2q flat [wi*4 + byt]
            const float* w2f = reinterpret_cast<const float*>(w2q) + wi * 4;
#pragma unroll
            for (int byt = 0; byt < 4; ++byt) {
                float fa = sbyte2f(aw[wi], byt);
                float fb = sbyte2f(bw[wi], byt);
                float s = fmaf(fb, sv, fa * su);
                s = fmaxf(s, 0.f);
                p = fmaf(s, w2f[byt], p);
            }
            (void)w2p;
        }
        p += __shfl_xor(p, 1);
        p += __shfl_xor(p, 2);
        if (sl == 0) out[e] = p + bias2;
    }
}

__global__ __launch_bounds__(256, 4) void edge_kernel(
    const long long* __restrict__ ei, const signed char* __restrict__ Aq,
    const signed char* __restrict__ Bq, const float* __restrict__ sA,
    const float* __restrict__ sB, const float* __restrict__ W2,
    const float* __restrict__ b2, float* __restrict__ out) {
    const int lane = threadIdx.x & 63;
    const int eg = lane >> 2;     // edge group 0..15 within wave
    const int sl = lane & 3;      // sub-lane within edge
    const float bias2 = b2[0];

    // int64-vs-int32 edge_index robustness probe (values < 1e5 -> hi words 0)
    const unsigned int hi = reinterpret_cast<const unsigned int*>(ei)[2 * lane + 1];
    const bool is64 = (__ballot(hi != 0) == 0ull);

    const int wid = (int)(((unsigned)(blockIdx.x * blockDim.x + threadIdx.x)) >> 6);
    const int nwaves = (int)(((unsigned)(gridDim.x * blockDim.x)) >> 6);

    if (is64) edge_loop<true>(ei, Aq, Bq, sA, sB, W2, bias2, out, wid, nwaves, eg, sl);
    else      edge_loop<false>(ei, Aq, Bq, sA, sB, W2, bias2, out, wid, nwaves, eg, sl);
}

extern "C" void kernel_launch(void* const* d_in, const int* in_sizes, int n_in,
                              void* d_out, int out_size, void* d_ws, size_t ws_size,
                              hipStream_t stream) {
    const float* x = (const float*)d_in[0];
    const long long* ei = (const long long*)d_in[1];
    const float* W1 = (const float*)d_in[2];
    const float* b1 = (const float*)d_in[3];
    const float* W2 = (const float*)d_in[4];
    const float* b2 = (const float*)d_in[5];
    float* out = (float*)d_out;

    signed char* Aq = (signed char*)d_ws;
    signed char* Bq = (signed char*)d_ws + BQ_OFF;
    float* sA = (float*)((char*)d_ws + SA_OFF);
    float* sB = (float*)((char*)d_ws + SB_OFF);

    dim3 g1(PRE_BLKX, 2);
    precompute_kernel<<<g1, 256, 0, stream>>>(x, W1, b1, Aq, Bq, sA, sB);
    edge_kernel<<<2048, 256, 0, stream>>>(ei, Aq, Bq, sA, sB, W2, b2, out);
}